// Round 1
// baseline (1054.698 us; speedup 1.0000x reference)
//
#include <hip/hip_runtime.h>
#include <stdint.h>

#define N_NODES 50000
#define N_EDGES 600000
#define DIM 128

typedef __attribute__((ext_vector_type(8))) short bf16x8;
typedef __attribute__((ext_vector_type(4))) float f32x4;
typedef __attribute__((ext_vector_type(4))) unsigned int u32x4;

__device__ inline unsigned short f2bf(float f) {
  unsigned u = __builtin_bit_cast(unsigned, f);
  unsigned r = 0x7fffu + ((u >> 16) & 1u);
  return (unsigned short)((u + r) >> 16);
}

// ---- LDS staging helpers (swizzled bf16 tiles, row stride 256 B) ----
// swizzle: byte_off_in_row ^= ((row&7)<<4)  -- breaks the 16-way bank conflict
// on ds_read_b128 across rows (guide §6 G4).

// stage a [64 x 128] f32 tile -> LDS bf16 (rows >= nvalid zero-filled)
__device__ inline void stage_tile_f32(const float* __restrict__ src, int row0,
                                      int nvalid, char* lds) {
#pragma unroll
  for (int it = 0; it < 4; ++it) {
    int c = it * 256 + threadIdx.x;      // 0..1023 chunks of 8 floats
    int row = c >> 4, f = c & 15;
    f32x4 v0 = {0,0,0,0}, v1 = {0,0,0,0};
    if (row < nvalid) {
      const f32x4* p = (const f32x4*)(src + (size_t)(row0 + row) * DIM + f * 8);
      v0 = p[0]; v1 = p[1];
    }
    u32x4 q;
    q[0] = (unsigned)f2bf(v0[0]) | ((unsigned)f2bf(v0[1]) << 16);
    q[1] = (unsigned)f2bf(v0[2]) | ((unsigned)f2bf(v0[3]) << 16);
    q[2] = (unsigned)f2bf(v1[0]) | ((unsigned)f2bf(v1[1]) << 16);
    q[3] = (unsigned)f2bf(v1[2]) | ((unsigned)f2bf(v1[3]) << 16);
    int byte = (f * 16) ^ ((row & 7) << 4);
    *(u32x4*)(lds + row * 256 + byte) = q;
  }
}

// stage a [128 x 128] bf16 weight matrix -> LDS (already bf16 in ws)
__device__ inline void stage_w(const unsigned short* __restrict__ wbf, char* lds) {
#pragma unroll
  for (int it = 0; it < 8; ++it) {
    int c = it * 256 + threadIdx.x;      // 0..2047 chunks of 8 bf16
    int row = c >> 4, f = c & 15;
    u32x4 q = *(const u32x4*)(wbf + row * 128 + f * 8);
    int byte = (f * 16) ^ ((row & 7) << 4);
    *(u32x4*)(lds + row * 256 + byte) = q;
  }
}

// read one MFMA input fragment: lane holds elem row=.., k = ks*32 + (l>>4)*8 + i
__device__ inline bf16x8 read_frag(const char* lds, int row, int ks, int lane) {
  int byte = ks * 64 + ((lane >> 4) * 16);
  byte ^= ((row & 7) << 4);
  return *(const bf16x8*)(lds + row * 256 + byte);
}

// ---- K0: fp32 -> bf16 weight conversion (A,B,C,D,E = 5 x 128x128) ----
__global__ void convert_weights(const float* __restrict__ a, const float* __restrict__ b,
                                const float* __restrict__ c, const float* __restrict__ d,
                                const float* __restrict__ e5, unsigned short* __restrict__ out) {
  int i = blockIdx.x * 256 + threadIdx.x;
  if (i >= 5 * 16384) return;
  int m = i >> 14, k = i & 16383;
  const float* p = (m == 0) ? a : (m == 1) ? b : (m == 2) ? c : (m == 3) ? d : e5;
  out[i] = f2bf(p[k]);
}

// ---- K1: node GEMMs: Ah/Bh/Dh/Eh = h @ W.T + b  (64 rows per block) ----
__global__ __launch_bounds__(256) void node_gemm(
    const float* __restrict__ h, const unsigned short* __restrict__ wbf,
    const float* __restrict__ Ab, const float* __restrict__ Bb,
    const float* __restrict__ Db, const float* __restrict__ Eb,
    float* __restrict__ Ah, float* __restrict__ Bh,
    float* __restrict__ Dh, float* __restrict__ Eh) {
  __shared__ __align__(16) char lds_x[64 * 256];
  __shared__ __align__(16) char lds_w[128 * 256];
  int tile = blockIdx.x * 64;
  int nvalid = N_NODES - tile; if (nvalid > 64) nvalid = 64;
  stage_tile_f32(h, tile, nvalid, lds_x);
  int lane = threadIdx.x & 63, w = threadIdx.x >> 6;
  int prow = w * 16 + (lane & 15);
  __syncthreads();
  bf16x8 a[4];
#pragma unroll
  for (int ks = 0; ks < 4; ++ks) a[ks] = read_frag(lds_x, prow, ks, lane);

  const int wmat[4] = {0, 1, 3, 4};           // A,B,D,E slots in wbf (C=2)
  float* const outs[4] = {Ah, Bh, Dh, Eh};
  const float* const biases[4] = {Ab, Bb, Db, Eb};
#pragma unroll
  for (int m = 0; m < 4; ++m) {
    __syncthreads();                           // previous lds_w reads done
    stage_w(wbf + wmat[m] * 16384, lds_w);
    __syncthreads();
    f32x4 acc[8] = {};
#pragma unroll
    for (int ct = 0; ct < 8; ++ct) {
#pragma unroll
      for (int ks = 0; ks < 4; ++ks) {
        bf16x8 b = read_frag(lds_w, ct * 16 + (lane & 15), ks, lane);
        acc[ct] = __builtin_amdgcn_mfma_f32_16x16x32_bf16(a[ks], b, acc[ct], 0, 0, 0);
      }
    }
    const float* bias = biases[m];
    float* out = outs[m];
#pragma unroll
    for (int ct = 0; ct < 8; ++ct) {
      int col = ct * 16 + (lane & 15);
      float bv = bias[col];
#pragma unroll
      for (int j = 0; j < 4; ++j) {
        int r = tile + w * 16 + (lane >> 4) * 4 + j;
        if (r < N_NODES) out[(size_t)r * DIM + col] = acc[ct][j] + bv;
      }
    }
  }
}

// ---- K2/K4: edge kernel. PHASE 0: stats + scatter. PHASE 1: BN apply + out ----
template <int PHASE>
__global__ __launch_bounds__(256) void edge_kernel(
    const float* __restrict__ e, const int* __restrict__ src, const int* __restrict__ dst,
    const unsigned short* __restrict__ wbf, const float* __restrict__ Cb,
    const float* __restrict__ Bh, const float* __restrict__ Dh, const float* __restrict__ Eh,
    float* __restrict__ acc_h, float* __restrict__ acc_s,
    float* __restrict__ stat_sum, float* __restrict__ stat_sum2,
    const float* __restrict__ scale_e, const float* __restrict__ shift_e,
    float* __restrict__ e_out) {
  __shared__ __align__(16) char lds_x[64 * 256];
  __shared__ __align__(16) char lds_w[128 * 256];
  __shared__ int s_src[64], s_dst[64];
  __shared__ float s_sum[128], s_sum2[128];
  int tile = blockIdx.x * 64;                 // E % 64 == 0, no tail
  stage_tile_f32(e, tile, 64, lds_x);
  stage_w(wbf + 2 * 16384, lds_w);
  if (threadIdx.x < 64) {
    s_src[threadIdx.x] = src[tile + threadIdx.x];
    s_dst[threadIdx.x] = dst[tile + threadIdx.x];
  }
  if (PHASE == 0 && threadIdx.x < 128) { s_sum[threadIdx.x] = 0.f; s_sum2[threadIdx.x] = 0.f; }
  __syncthreads();
  int lane = threadIdx.x & 63, w = threadIdx.x >> 6;
  int prow = w * 16 + (lane & 15);
  bf16x8 a[4];
#pragma unroll
  for (int ks = 0; ks < 4; ++ks) a[ks] = read_frag(lds_x, prow, ks, lane);
  f32x4 acc[8] = {};
#pragma unroll
  for (int ct = 0; ct < 8; ++ct) {
#pragma unroll
    for (int ks = 0; ks < 4; ++ks) {
      bf16x8 b = read_frag(lds_w, ct * 16 + (lane & 15), ks, lane);
      acc[ct] = __builtin_amdgcn_mfma_f32_16x16x32_bf16(a[ks], b, acc[ct], 0, 0, 0);
    }
  }
#pragma unroll
  for (int ct = 0; ct < 8; ++ct) {
    int col = ct * 16 + (lane & 15);
    float cb = Cb[col];
    float ssum = 0.f, ssum2 = 0.f;
    float sc = 0.f, sh = 0.f;
    if (PHASE == 1) { sc = scale_e[col]; sh = shift_e[col]; }
#pragma unroll
    for (int j = 0; j < 4; ++j) {
      int rl = w * 16 + (lane >> 4) * 4 + j;   // row within tile
      int s = s_src[rl], d = s_dst[rl];
      float enew = acc[ct][j] + cb + Dh[s * DIM + col] + Eh[d * DIM + col];
      if (PHASE == 0) {
        float sig = 1.f / (1.f + __expf(-enew));
        float m = Bh[s * DIM + col] * sig;
        atomicAdd(acc_h + d * DIM + col, m);
        atomicAdd(acc_s + d * DIM + col, sig);
        ssum += enew; ssum2 += enew * enew;
      } else {
        int er = tile + rl;
        float y = enew * sc + sh;
        y = fmaxf(y, 0.f) + e[(size_t)er * DIM + col];
        e_out[(size_t)er * DIM + col] = y;
      }
    }
    if (PHASE == 0) {
      ssum  += __shfl_xor(ssum, 16);  ssum  += __shfl_xor(ssum, 32);
      ssum2 += __shfl_xor(ssum2, 16); ssum2 += __shfl_xor(ssum2, 32);
      if (lane < 16) { atomicAdd(&s_sum[col], ssum); atomicAdd(&s_sum2[col], ssum2); }
    }
  }
  if (PHASE == 0) {
    __syncthreads();
    if (threadIdx.x < 128) {
      atomicAdd(stat_sum + threadIdx.x, s_sum[threadIdx.x]);
      atomicAdd(stat_sum2 + threadIdx.x, s_sum2[threadIdx.x]);
    }
  }
}

// ---- K5a: h_new pre-activation + BN-h stats ----
__global__ __launch_bounds__(256) void node_pre(
    const float* __restrict__ Ah, const float* __restrict__ acc_h,
    const float* __restrict__ acc_s, float* __restrict__ pre_out,
    float* __restrict__ stat_sum, float* __restrict__ stat_sum2) {
  __shared__ float s_sum[128], s_sum2[128];
  if (threadIdx.x < 128) { s_sum[threadIdx.x] = 0.f; s_sum2[threadIdx.x] = 0.f; }
  __syncthreads();
  const int total4 = N_NODES * DIM / 4;
  float ls[4] = {0, 0, 0, 0}, lq[4] = {0, 0, 0, 0};
  int colbase = (threadIdx.x & 31) * 4;       // stride is a multiple of 32
  for (int i = blockIdx.x * blockDim.x + threadIdx.x; i < total4;
       i += gridDim.x * blockDim.x) {
    f32x4 a = ((const f32x4*)Ah)[i];
    f32x4 mh = ((const f32x4*)acc_h)[i];
    f32x4 ms = ((const f32x4*)acc_s)[i];
    f32x4 p;
#pragma unroll
    for (int j = 0; j < 4; ++j) {
      p[j] = a[j] + mh[j] / (ms[j] + 1e-6f);
      ls[j] += p[j]; lq[j] += p[j] * p[j];
    }
    ((f32x4*)pre_out)[i] = p;
  }
#pragma unroll
  for (int j = 0; j < 4; ++j) {
    atomicAdd(&s_sum[colbase + j], ls[j]);
    atomicAdd(&s_sum2[colbase + j], lq[j]);
  }
  __syncthreads();
  if (threadIdx.x < 128) {
    atomicAdd(stat_sum + threadIdx.x, s_sum[threadIdx.x]);
    atomicAdd(stat_sum2 + threadIdx.x, s_sum2[threadIdx.x]);
  }
}

// ---- K3: per-column BN scale/shift from sums ----
__global__ void finalize_stats(const float* __restrict__ sum, const float* __restrict__ sum2,
                               const float* __restrict__ gamma, const float* __restrict__ beta,
                               float count, float* __restrict__ scale, float* __restrict__ shift) {
  int c = threadIdx.x;
  if (c < 128) {
    float mu = sum[c] / count;
    float var = sum2[c] / count - mu * mu;
    float inv = rsqrtf(var + 1e-5f);
    float sc = gamma[c] * inv;
    scale[c] = sc;
    shift[c] = beta[c] - mu * sc;
  }
}

// ---- K5c: h_out = h + relu(pre*scale + shift) (in place on d_out h region) ----
__global__ __launch_bounds__(256) void node_final(
    const float* __restrict__ h, float* __restrict__ hout,
    const float* __restrict__ scale, const float* __restrict__ shift) {
  const int total4 = N_NODES * DIM / 4;
  for (int i = blockIdx.x * blockDim.x + threadIdx.x; i < total4;
       i += gridDim.x * blockDim.x) {
    f32x4 p = ((const f32x4*)hout)[i];
    f32x4 hv = ((const f32x4*)h)[i];
    f32x4 sc4 = ((const f32x4*)scale)[i & 31];
    f32x4 sh4 = ((const f32x4*)shift)[i & 31];
    f32x4 o;
#pragma unroll
    for (int j = 0; j < 4; ++j) {
      float y = p[j] * sc4[j] + sh4[j];
      o[j] = hv[j] + fmaxf(y, 0.f);
    }
    ((f32x4*)hout)[i] = o;
  }
}

extern "C" void kernel_launch(void* const* d_in, const int* in_sizes, int n_in,
                              void* d_out, int out_size, void* d_ws, size_t ws_size,
                              hipStream_t stream) {
  const float* h   = (const float*)d_in[0];
  const float* e   = (const float*)d_in[1];
  const int*   src = (const int*)d_in[2];
  const int*   dst = (const int*)d_in[3];
  const float* Aw = (const float*)d_in[4];  const float* Ab = (const float*)d_in[5];
  const float* Bw = (const float*)d_in[6];  const float* Bb = (const float*)d_in[7];
  const float* Cw = (const float*)d_in[8];  const float* Cb = (const float*)d_in[9];
  const float* Dw = (const float*)d_in[10]; const float* Db = (const float*)d_in[11];
  const float* Ew = (const float*)d_in[12]; const float* Eb = (const float*)d_in[13];
  const float* bn_h_g = (const float*)d_in[14]; const float* bn_h_b = (const float*)d_in[15];
  const float* bn_e_g = (const float*)d_in[16]; const float* bn_e_b = (const float*)d_in[17];

  const size_t ND = (size_t)N_NODES * DIM * 4;   // 25.6 MB
  char* ws = (char*)d_ws;
  unsigned short* wbf = (unsigned short*)ws;      // 5*16384*2 = 163840 B
  size_t off = 163840;
  float* Ah = (float*)(ws + off); off += ND;
  float* Bh = (float*)(ws + off); off += ND;
  float* Dh = (float*)(ws + off); off += ND;
  float* Eh = (float*)(ws + off); off += ND;
  float* acc_h = (float*)(ws + off); off += ND;
  float* acc_s = (float*)(ws + off); off += ND;
  float* stats = (float*)(ws + off);              // 8 x 128 floats
  float* e_sum = stats, *e_sum2 = stats + 128;
  float* h_sum = stats + 256, *h_sum2 = stats + 384;
  float* scale_e = stats + 512, *shift_e = stats + 640;
  float* scale_h = stats + 768, *shift_h = stats + 896;

  float* hout = (float*)d_out;
  float* eout = (float*)d_out + (size_t)N_NODES * DIM;

  hipMemsetAsync(acc_h, 0, 2 * ND, stream);       // acc_h + acc_s contiguous
  hipMemsetAsync(stats, 0, 4 * 128 * sizeof(float), stream);

  convert_weights<<<320, 256, 0, stream>>>(Aw, Bw, Cw, Dw, Ew, wbf);
  node_gemm<<<(N_NODES + 63) / 64, 256, 0, stream>>>(h, wbf, Ab, Bb, Db, Eb, Ah, Bh, Dh, Eh);
  edge_kernel<0><<<N_EDGES / 64, 256, 0, stream>>>(e, src, dst, wbf, Cb, Bh, Dh, Eh,
      acc_h, acc_s, e_sum, e_sum2, nullptr, nullptr, nullptr);
  finalize_stats<<<1, 128, 0, stream>>>(e_sum, e_sum2, bn_e_g, bn_e_b, (float)N_EDGES,
      scale_e, shift_e);
  node_pre<<<1024, 256, 0, stream>>>(Ah, acc_h, acc_s, hout, h_sum, h_sum2);
  finalize_stats<<<1, 128, 0, stream>>>(h_sum, h_sum2, bn_h_g, bn_h_b, (float)N_NODES,
      scale_h, shift_h);
  edge_kernel<1><<<N_EDGES / 64, 256, 0, stream>>>(e, src, dst, wbf, Cb, Bh, Dh, Eh,
      nullptr, nullptr, nullptr, nullptr, scale_e, shift_e, eout);
  node_final<<<1024, 256, 0, stream>>>(h, hout, scale_h, shift_h);
}